// Round 1
// baseline (947.813 us; speedup 1.0000x reference)
//
#include <hip/hip_runtime.h>
#include <hip/hip_bf16.h>

// Problem constants
// B=128, S=256, E=768, C=4
// M = B*S = 32768 rows through the MLP.
//
// Pipeline:
//  K1 (gemm): qW1[128,768]  = questions @ W1[:768] + b1          (no gelu)
//  K2 (gemm): H1[32768,768] = gelu(segments @ W1[768:] + qW1[b])
//  K3 (gemm): H2[32768,384] = gelu(H1 @ W2 + b2)
//  K4:        preds[32768,4] = softmax(H2 @ W3 + b3)
//  K5:        out[128,4] = noisy-OR aggregation (scan-based)

#define BM 64
#define BN 64
#define BK 16

__device__ __forceinline__ float gelu_exact(float x) {
    return 0.5f * x * (1.0f + erff(x * 0.70710678118654752440f));
}

__global__ __launch_bounds__(256) void gemm_bias_act(
    const float* __restrict__ A, const float* __restrict__ Bw,
    const float* __restrict__ bias,     // [N] or null
    const float* __restrict__ rowAdd,   // [M/256, N] (per-bag add) or null
    float* __restrict__ Cout, int Mdim, int Ndim, int Kdim, int applyGelu)
{
    __shared__ __align__(16) float As[BK][BM];
    __shared__ __align__(16) float Bs[BK][BN];
    const int tid = threadIdx.x;
    const int n0 = blockIdx.x * BN;
    const int m0 = blockIdx.y * BM;
    const int tn = tid & 15, tm = tid >> 4;

    float acc[4][4] = {};

    const int la_m = tid >> 2;          // 0..63
    const int la_k = (tid & 3) << 2;    // 0,4,8,12
    const int lb_k = tid >> 4;          // 0..15
    const int lb_n = (tid & 15) << 2;   // 0..60

    const float* Aptr = A + (size_t)(m0 + la_m) * Kdim + la_k;
    const float* Bptr = Bw + (size_t)lb_k * Ndim + n0 + lb_n;

    for (int k0 = 0; k0 < Kdim; k0 += BK) {
        float4 av = *(const float4*)(Aptr + k0);
        float4 bv = *(const float4*)(Bptr + (size_t)k0 * Ndim);
        As[la_k + 0][la_m] = av.x;
        As[la_k + 1][la_m] = av.y;
        As[la_k + 2][la_m] = av.z;
        As[la_k + 3][la_m] = av.w;
        *(float4*)&Bs[lb_k][lb_n] = bv;
        __syncthreads();
        #pragma unroll
        for (int k = 0; k < BK; k++) {
            float4 a = *(const float4*)&As[k][tm << 2];
            float4 b = *(const float4*)&Bs[k][tn << 2];
            float ar[4] = {a.x, a.y, a.z, a.w};
            float br[4] = {b.x, b.y, b.z, b.w};
            #pragma unroll
            for (int i = 0; i < 4; i++)
                #pragma unroll
                for (int j = 0; j < 4; j++)
                    acc[i][j] += ar[i] * br[j];
        }
        __syncthreads();
    }

    #pragma unroll
    for (int i = 0; i < 4; i++) {
        int row = m0 + (tm << 2) + i;
        int colBase = n0 + (tn << 2);
        const float* radd = rowAdd ? (rowAdd + (size_t)(row >> 8) * Ndim) : nullptr;
        float vals[4];
        #pragma unroll
        for (int j = 0; j < 4; j++) {
            float v = acc[i][j];
            int col = colBase + j;
            if (bias) v += bias[col];
            if (radd) v += radd[col];
            if (applyGelu) v = gelu_exact(v);
            vals[j] = v;
        }
        *(float4*)&Cout[(size_t)row * Ndim + colBase] =
            make_float4(vals[0], vals[1], vals[2], vals[3]);
    }
}

// Layer 3 + softmax: one wave per row.
__global__ __launch_bounds__(256) void l3_softmax(
    const float* __restrict__ H2, const float* __restrict__ W3,
    const float* __restrict__ b3, float* __restrict__ preds)
{
    __shared__ float w3s[4 * 384];   // transposed: w3s[c*384 + k]
    const int tid = threadIdx.x;
    for (int i = tid; i < 1536; i += 256) {
        int k = i >> 2, c = i & 3;
        w3s[c * 384 + k] = W3[i];
    }
    __syncthreads();
    const int wave = tid >> 6, lane = tid & 63;
    const int row = blockIdx.x * 4 + wave;

    float h[6];
    #pragma unroll
    for (int t = 0; t < 6; t++) h[t] = H2[(size_t)row * 384 + lane + 64 * t];

    float a0 = 0.f, a1 = 0.f, a2 = 0.f, a3 = 0.f;
    #pragma unroll
    for (int t = 0; t < 6; t++) {
        int k = lane + 64 * t;
        float hv = h[t];
        a0 += hv * w3s[k];
        a1 += hv * w3s[384 + k];
        a2 += hv * w3s[768 + k];
        a3 += hv * w3s[1152 + k];
    }
    #pragma unroll
    for (int off = 32; off > 0; off >>= 1) {
        a0 += __shfl_xor(a0, off, 64);
        a1 += __shfl_xor(a1, off, 64);
        a2 += __shfl_xor(a2, off, 64);
        a3 += __shfl_xor(a3, off, 64);
    }
    if (lane == 0) {
        float z0 = a0 + b3[0], z1 = a1 + b3[1], z2 = a2 + b3[2], z3 = a3 + b3[3];
        float m = fmaxf(fmaxf(z0, z1), fmaxf(z2, z3));
        float e0 = expf(z0 - m), e1 = expf(z1 - m), e2 = expf(z2 - m), e3 = expf(z3 - m);
        float inv = 1.0f / (e0 + e1 + e2 + e3);
        ((float4*)preds)[row] = make_float4(e0 * inv, e1 * inv, e2 * inv, e3 * inv);
    }
}

__device__ __forceinline__ float4 f4mul(float4 a, float4 b) {
    return make_float4(a.x * b.x, a.y * b.y, a.z * b.z, a.w * b.w);
}

// Inclusive product scan over 256 threads (Hillis-Steele). Leaves result in buf.
__device__ float4 scan_prod(float4 v, float4* buf, int tid) {
    __syncthreads();
    buf[tid] = v;
    __syncthreads();
    #pragma unroll
    for (int off = 1; off < 256; off <<= 1) {
        float4 o = (tid >= off) ? buf[tid - off] : make_float4(1.f, 1.f, 1.f, 1.f);
        __syncthreads();
        v = f4mul(v, o);
        buf[tid] = v;
        __syncthreads();
    }
    return v;
}

__global__ __launch_bounds__(256) void aggregate(
    const float* __restrict__ preds, const int* __restrict__ nseg,
    float* __restrict__ out)
{
    __shared__ float4 buf[256];
    const int b = blockIdx.x, tid = threadIdx.x;
    const int n = nseg[b];
    const float4 ones = make_float4(1.f, 1.f, 1.f, 1.f);

    float4 p = ((const float4*)preds)[b * 256 + tid];
    bool msk = tid < n;
    float e1 = p.x, e2 = e1 + p.y, e3 = e2 + p.z;
    float4 sm = msk ? make_float4(0.f, e1, e2, e3) : ones;

    // forward inclusive cumprod -> exclusive prefix
    scan_prod(sm, buf, tid);
    float4 pfx = (tid > 0) ? buf[tid - 1] : ones;
    __syncthreads();

    // reversed inclusive cumprod -> exclusive suffix
    buf[255 - tid] = sm;
    __syncthreads();
    float4 rsm = buf[tid];
    scan_prod(rsm, buf, tid);                 // buf[t] = cpB_{255-t}
    float4 sfx = (tid < 255) ? buf[254 - tid] : ones;

    float4 L = f4mul(pfx, sfx);               // leave-one-out product
    float4 cpL = scan_prod(L, buf, tid);      // running product over i

    float4 term = msk ? f4mul(p, cpL) : make_float4(0.f, 0.f, 0.f, 0.f);
    float4 pm = msk ? p : ones;

    // sum reduction of term
    __syncthreads();
    buf[tid] = term;
    __syncthreads();
    for (int off = 128; off > 0; off >>= 1) {
        if (tid < off) {
            float4 a = buf[tid], c = buf[tid + off];
            buf[tid] = make_float4(a.x + c.x, a.y + c.y, a.z + c.z, a.w + c.w);
        }
        __syncthreads();
    }
    float4 sum_t = buf[0];   // valid for tid==0 use below
    __syncthreads();

    // product reduction of pm
    buf[tid] = pm;
    __syncthreads();
    for (int off = 128; off > 0; off >>= 1) {
        if (tid < off) buf[tid] = f4mul(buf[tid], buf[tid + off]);
        __syncthreads();
    }
    if (tid == 0) {
        float4 pr = buf[0];
        ((float4*)out)[b] = make_float4(0.25f * sum_t.x + pr.x,
                                        0.25f * sum_t.y + pr.y,
                                        0.25f * sum_t.z + pr.z,
                                        0.25f * sum_t.w + pr.w);
    }
}

extern "C" void kernel_launch(void* const* d_in, const int* in_sizes, int n_in,
                              void* d_out, int out_size, void* d_ws, size_t ws_size,
                              hipStream_t stream) {
    (void)in_sizes; (void)n_in; (void)out_size; (void)ws_size;
    const float* questions = (const float*)d_in[0];   // [128,768]
    const float* segments  = (const float*)d_in[1];   // [128,256,768]
    const float* W1 = (const float*)d_in[2];          // [1536,768]
    const float* b1 = (const float*)d_in[3];          // [768]
    const float* W2 = (const float*)d_in[4];          // [768,384]
    const float* b2 = (const float*)d_in[5];          // [384]
    const float* W3 = (const float*)d_in[6];          // [384,4]
    const float* b3 = (const float*)d_in[7];          // [4]
    const int*  nseg = (const int*)d_in[8];           // [128]
    float* out = (float*)d_out;

    float* ws   = (float*)d_ws;
    float* qW1  = ws;                                  // 128*768
    float* H1   = qW1 + 128 * 768;                     // 32768*768
    float* H2   = H1 + (size_t)32768 * 768;            // 32768*384
    float* preds = H2 + (size_t)32768 * 384;           // 32768*4

    // K1: qW1 = questions @ W1[:768] + b1 (no gelu)
    gemm_bias_act<<<dim3(768 / BN, 128 / BM), 256, 0, stream>>>(
        questions, W1, b1, nullptr, qW1, 128, 768, 768, 0);
    // K2: H1 = gelu(segments @ W1[768:] + qW1[row>>8])
    gemm_bias_act<<<dim3(768 / BN, 32768 / BM), 256, 0, stream>>>(
        segments, W1 + 768 * 768, nullptr, qW1, H1, 32768, 768, 768, 1);
    // K3: H2 = gelu(H1 @ W2 + b2)
    gemm_bias_act<<<dim3(384 / BN, 32768 / BM), 256, 0, stream>>>(
        H1, W2, b2, nullptr, H2, 32768, 384, 768, 1);
    // K4: preds = softmax(H2 @ W3 + b3)
    l3_softmax<<<8192, 256, 0, stream>>>(H2, W3, b3, preds);
    // K5: aggregation
    aggregate<<<128, 256, 0, stream>>>(preds, nseg, out);
}

// Round 2
// 376.498 us; speedup vs baseline: 2.5174x; 2.5174x over previous
//
#include <hip/hip_runtime.h>
#include <hip/hip_bf16.h>

// B=128, S=256, E=768, C=4; M = B*S = 32768.
// Pipeline:
//  conv:  segB[32768,768]bf16 = bf16(segments)
//  tr:    W1t[768,768]bf16 = bf16(W1[768:,:].T);  W2t[384,768]bf16 = bf16(W2.T)
//  K1:    qW1[128,768]f32 = questions @ W1[:768] + b1            (fp32 vector gemm)
//  K2:    H1b[32768,768]bf16 = gelu(segB @ W1t^T + qW1[bag])     (MFMA)
//  K3:    H2b[32768,384]bf16 = gelu(H1b @ W2t^T + b2)            (MFMA)
//  K4:    preds[32768,4]f32 = softmax(H2b @ W3 + b3)
//  K5:    out[128,4] = noisy-OR aggregation (scans)

typedef __attribute__((ext_vector_type(8))) short short8;
typedef __attribute__((ext_vector_type(8))) unsigned short ushort8;
typedef __attribute__((ext_vector_type(4))) float f32x4;

__device__ __forceinline__ unsigned short f2bf(float f) {
    union { float f; unsigned int u; } c; c.f = f;
    unsigned int u = c.u;
    unsigned int r = (u + 0x7FFFu + ((u >> 16) & 1u)) >> 16;  // RNE
    return (unsigned short)r;
}
__device__ __forceinline__ float bf2f(unsigned short u) {
    union { unsigned int u; float f; } c; c.u = ((unsigned int)u) << 16;
    return c.f;
}
__device__ __forceinline__ float gelu_exact(float x) {
    return 0.5f * x * (1.0f + erff(x * 0.70710678118654752440f));
}

typedef const __attribute__((address_space(1))) void* gas_t;
typedef __attribute__((address_space(3))) void* las_t;
__device__ __forceinline__ void g2l16(const void* g, void* l) {
    __builtin_amdgcn_global_load_lds((gas_t)g, (las_t)l, 16, 0, 0);
}

// ---------------- conversion kernels ----------------
__global__ __launch_bounds__(256) void conv_f32_bf16x8(
    const float4* __restrict__ in, unsigned short* __restrict__ out, long n8)
{
    long i = (long)blockIdx.x * 256 + threadIdx.x;
    if (i >= n8) return;
    float4 a = in[2 * i], b = in[2 * i + 1];
    ushort8 o;
    o[0] = f2bf(a.x); o[1] = f2bf(a.y); o[2] = f2bf(a.z); o[3] = f2bf(a.w);
    o[4] = f2bf(b.x); o[5] = f2bf(b.y); o[6] = f2bf(b.z); o[7] = f2bf(b.w);
    *(ushort8*)(out + i * 8) = o;
}

// out[c*R + r] = bf16(in[r*C + c])
__global__ __launch_bounds__(256) void transpose_f32_bf16(
    const float* __restrict__ in, unsigned short* __restrict__ out, int R, int C)
{
    __shared__ float t[64][65];
    int r0 = blockIdx.y * 64, c0 = blockIdx.x * 64;
    int tx = threadIdx.x & 63, ty = threadIdx.x >> 6;   // ty in 0..3
    #pragma unroll
    for (int p = 0; p < 16; p++) {
        int row = ty * 16 + p;
        t[row][tx] = in[(size_t)(r0 + row) * C + c0 + tx];
    }
    __syncthreads();
    #pragma unroll
    for (int p = 0; p < 16; p++) {
        int orow = ty * 16 + p;   // c index
        out[(size_t)(c0 + orow) * R + r0 + tx] = f2bf(t[tx][orow]);
    }
}

// ---------------- fp32 vector GEMM (for tiny K1) ----------------
#define BM 64
#define BN 64
#define BK 16
__global__ __launch_bounds__(256) void gemm_bias_act(
    const float* __restrict__ A, const float* __restrict__ Bw,
    const float* __restrict__ bias, float* __restrict__ Cout,
    int Mdim, int Ndim, int Kdim)
{
    __shared__ __align__(16) float As[BK][BM];
    __shared__ __align__(16) float Bs[BK][BN];
    const int tid = threadIdx.x;
    const int n0 = blockIdx.x * BN;
    const int m0 = blockIdx.y * BM;
    const int tn = tid & 15, tm = tid >> 4;
    float acc[4][4] = {};
    const int la_m = tid >> 2;
    const int la_k = (tid & 3) << 2;
    const int lb_k = tid >> 4;
    const int lb_n = (tid & 15) << 2;
    const float* Aptr = A + (size_t)(m0 + la_m) * Kdim + la_k;
    const float* Bptr = Bw + (size_t)lb_k * Ndim + n0 + lb_n;
    for (int k0 = 0; k0 < Kdim; k0 += BK) {
        float4 av = *(const float4*)(Aptr + k0);
        float4 bv = *(const float4*)(Bptr + (size_t)k0 * Ndim);
        As[la_k + 0][la_m] = av.x;
        As[la_k + 1][la_m] = av.y;
        As[la_k + 2][la_m] = av.z;
        As[la_k + 3][la_m] = av.w;
        *(float4*)&Bs[lb_k][lb_n] = bv;
        __syncthreads();
        #pragma unroll
        for (int k = 0; k < BK; k++) {
            float4 a = *(const float4*)&As[k][tm << 2];
            float4 b = *(const float4*)&Bs[k][tn << 2];
            float ar[4] = {a.x, a.y, a.z, a.w};
            float br[4] = {b.x, b.y, b.z, b.w};
            #pragma unroll
            for (int i = 0; i < 4; i++)
                #pragma unroll
                for (int j = 0; j < 4; j++)
                    acc[i][j] += ar[i] * br[j];
        }
        __syncthreads();
    }
    #pragma unroll
    for (int i = 0; i < 4; i++) {
        int row = m0 + (tm << 2) + i;
        int colBase = n0 + (tn << 2);
        float vals[4];
        #pragma unroll
        for (int j = 0; j < 4; j++)
            vals[j] = acc[i][j] + bias[colBase + j];
        *(float4*)&Cout[(size_t)row * Ndim + colBase] =
            make_float4(vals[0], vals[1], vals[2], vals[3]);
    }
}

// ---------------- bf16 MFMA GEMM, B^T input ----------------
// C[M,N] = act(A[M,K] @ Bt[N,K]^T + bias + rowAdd[m>>8])  -> bf16
__global__ __launch_bounds__(256) void mfma_gemm_bt(
    const unsigned short* __restrict__ A,    // [M,K] bf16
    const unsigned short* __restrict__ Bt,   // [N,K] bf16
    const float* __restrict__ bias,          // [N] or null
    const float* __restrict__ rowAdd,        // [M/256, N] or null
    unsigned short* __restrict__ Cout,       // [M,N] bf16
    int M, int N, int K, int applyGelu)
{
    __shared__ __align__(16) unsigned short As[128 * 32];  // [row][k] 32-elem rows
    __shared__ __align__(16) unsigned short Bs[128 * 32];  // [n][k]
    const int tid = threadIdx.x;
    const int wave = tid >> 6, lane = tid & 63;
    const int m0 = blockIdx.y * 128, n0 = blockIdx.x * 128;
    const int wm = (wave & 1) * 64, wn = (wave >> 1) * 64;

    f32x4 acc[4][4] = {};

    const int r0 = tid >> 2;           // 0..63
    const int c0 = (tid & 3) * 8;      // 0,8,16,24
    const unsigned short* Ag = A + (size_t)(m0 + r0) * K + c0;
    const unsigned short* Ag2 = Ag + (size_t)64 * K;
    const unsigned short* Bg = Bt + (size_t)(n0 + r0) * K + c0;
    const unsigned short* Bg2 = Bg + (size_t)64 * K;
    unsigned short* Al = As + tid * 8;
    unsigned short* Bl = Bs + tid * 8;

    const int fr = lane & 15, fq = lane >> 4;

    for (int k0 = 0; k0 < K; k0 += 32) {
        g2l16(Ag + k0, Al);
        g2l16(Ag2 + k0, Al + 2048);
        g2l16(Bg + k0, Bl);
        g2l16(Bg2 + k0, Bl + 2048);
        __syncthreads();

        short8 af[4], bfr[4];
        #pragma unroll
        for (int i = 0; i < 4; i++)
            af[i] = *(const short8*)&As[(wm + i * 16 + fr) * 32 + fq * 8];
        #pragma unroll
        for (int j = 0; j < 4; j++)
            bfr[j] = *(const short8*)&Bs[(wn + j * 16 + fr) * 32 + fq * 8];
        #pragma unroll
        for (int i = 0; i < 4; i++)
            #pragma unroll
            for (int j = 0; j < 4; j++)
                acc[i][j] = __builtin_amdgcn_mfma_f32_16x16x32_bf16(
                    af[i], bfr[j], acc[i][j], 0, 0, 0);
        __syncthreads();
    }

    // epilogue: C/D layout col=lane&15, row=(lane>>4)*4+reg
    const float* radd = rowAdd ? (rowAdd + (size_t)(m0 >> 8) * N) : nullptr;
    const int cn = lane & 15, cq = lane >> 4;
    #pragma unroll
    for (int j = 0; j < 4; j++) {
        int col = n0 + wn + j * 16 + cn;
        float add = (bias ? bias[col] : 0.0f) + (radd ? radd[col] : 0.0f);
        #pragma unroll
        for (int i = 0; i < 4; i++) {
            int rowb = m0 + wm + i * 16 + cq * 4;
            #pragma unroll
            for (int r = 0; r < 4; r++) {
                float v = acc[i][j][r] + add;
                if (applyGelu) v = gelu_exact(v);
                Cout[(size_t)(rowb + r) * N + col] = f2bf(v);
            }
        }
    }
}

// ---------------- layer3 + softmax (bf16 input) ----------------
__global__ __launch_bounds__(256) void l3_softmax(
    const unsigned short* __restrict__ H2, const float* __restrict__ W3,
    const float* __restrict__ b3, float* __restrict__ preds)
{
    __shared__ float w3s[4 * 384];
    const int tid = threadIdx.x;
    for (int i = tid; i < 1536; i += 256) {
        int k = i >> 2, c = i & 3;
        w3s[c * 384 + k] = W3[i];
    }
    __syncthreads();
    const int wave = tid >> 6, lane = tid & 63;
    const int row = blockIdx.x * 4 + wave;

    float h[6];
    #pragma unroll
    for (int t = 0; t < 6; t++) h[t] = bf2f(H2[(size_t)row * 384 + lane + 64 * t]);

    float a0 = 0.f, a1 = 0.f, a2 = 0.f, a3 = 0.f;
    #pragma unroll
    for (int t = 0; t < 6; t++) {
        int k = lane + 64 * t;
        float hv = h[t];
        a0 += hv * w3s[k];
        a1 += hv * w3s[384 + k];
        a2 += hv * w3s[768 + k];
        a3 += hv * w3s[1152 + k];
    }
    #pragma unroll
    for (int off = 32; off > 0; off >>= 1) {
        a0 += __shfl_xor(a0, off, 64);
        a1 += __shfl_xor(a1, off, 64);
        a2 += __shfl_xor(a2, off, 64);
        a3 += __shfl_xor(a3, off, 64);
    }
    if (lane == 0) {
        float z0 = a0 + b3[0], z1 = a1 + b3[1], z2 = a2 + b3[2], z3 = a3 + b3[3];
        float m = fmaxf(fmaxf(z0, z1), fmaxf(z2, z3));
        float e0 = expf(z0 - m), e1 = expf(z1 - m), e2 = expf(z2 - m), e3 = expf(z3 - m);
        float inv = 1.0f / (e0 + e1 + e2 + e3);
        ((float4*)preds)[row] = make_float4(e0 * inv, e1 * inv, e2 * inv, e3 * inv);
    }
}

// ---------------- aggregation ----------------
__device__ __forceinline__ float4 f4mul(float4 a, float4 b) {
    return make_float4(a.x * b.x, a.y * b.y, a.z * b.z, a.w * b.w);
}
__device__ float4 scan_prod(float4 v, float4* buf, int tid) {
    __syncthreads();
    buf[tid] = v;
    __syncthreads();
    #pragma unroll
    for (int off = 1; off < 256; off <<= 1) {
        float4 o = (tid >= off) ? buf[tid - off] : make_float4(1.f, 1.f, 1.f, 1.f);
        __syncthreads();
        v = f4mul(v, o);
        buf[tid] = v;
        __syncthreads();
    }
    return v;
}

__global__ __launch_bounds__(256) void aggregate(
    const float* __restrict__ preds, const int* __restrict__ nseg,
    float* __restrict__ out)
{
    __shared__ float4 buf[256];
    const int b = blockIdx.x, tid = threadIdx.x;
    const int n = nseg[b];
    const float4 ones = make_float4(1.f, 1.f, 1.f, 1.f);

    float4 p = ((const float4*)preds)[b * 256 + tid];
    bool msk = tid < n;
    float e1 = p.x, e2 = e1 + p.y, e3 = e2 + p.z;
    float4 sm = msk ? make_float4(0.f, e1, e2, e3) : ones;

    scan_prod(sm, buf, tid);
    float4 pfx = (tid > 0) ? buf[tid - 1] : ones;
    __syncthreads();

    buf[255 - tid] = sm;
    __syncthreads();
    float4 rsm = buf[tid];
    scan_prod(rsm, buf, tid);
    float4 sfx = (tid < 255) ? buf[254 - tid] : ones;

    float4 L = f4mul(pfx, sfx);
    float4 cpL = scan_prod(L, buf, tid);

    float4 term = msk ? f4mul(p, cpL) : make_float4(0.f, 0.f, 0.f, 0.f);
    float4 pm = msk ? p : ones;

    __syncthreads();
    buf[tid] = term;
    __syncthreads();
    for (int off = 128; off > 0; off >>= 1) {
        if (tid < off) {
            float4 a = buf[tid], c = buf[tid + off];
            buf[tid] = make_float4(a.x + c.x, a.y + c.y, a.z + c.z, a.w + c.w);
        }
        __syncthreads();
    }
    float4 sum_t = buf[0];
    __syncthreads();

    buf[tid] = pm;
    __syncthreads();
    for (int off = 128; off > 0; off >>= 1) {
        if (tid < off) buf[tid] = f4mul(buf[tid], buf[tid + off]);
        __syncthreads();
    }
    if (tid == 0) {
        float4 pr = buf[0];
        ((float4*)out)[b] = make_float4(0.25f * sum_t.x + pr.x,
                                        0.25f * sum_t.y + pr.y,
                                        0.25f * sum_t.z + pr.z,
                                        0.25f * sum_t.w + pr.w);
    }
}

extern "C" void kernel_launch(void* const* d_in, const int* in_sizes, int n_in,
                              void* d_out, int out_size, void* d_ws, size_t ws_size,
                              hipStream_t stream) {
    (void)in_sizes; (void)n_in; (void)out_size; (void)ws_size;
    const float* questions = (const float*)d_in[0];
    const float* segments  = (const float*)d_in[1];
    const float* W1 = (const float*)d_in[2];
    const float* b1 = (const float*)d_in[3];
    const float* W2 = (const float*)d_in[4];
    const float* b2 = (const float*)d_in[5];
    const float* W3 = (const float*)d_in[6];
    const float* b3 = (const float*)d_in[7];
    const int*  nseg = (const int*)d_in[8];
    float* out = (float*)d_out;

    char* w = (char*)d_ws;
    float* qW1 = (float*)w;            w += (size_t)128 * 768 * 4;
    unsigned short* W1t = (unsigned short*)w; w += (size_t)768 * 768 * 2;
    unsigned short* W2t = (unsigned short*)w; w += (size_t)384 * 768 * 2;
    unsigned short* segB = (unsigned short*)w; w += (size_t)32768 * 768 * 2;
    unsigned short* H1b  = (unsigned short*)w; w += (size_t)32768 * 768 * 2;
    unsigned short* H2b  = (unsigned short*)w; w += (size_t)32768 * 384 * 2;
    float* preds = (float*)w;          w += (size_t)32768 * 4 * 4;

    // conversions
    conv_f32_bf16x8<<<12288, 256, 0, stream>>>((const float4*)segments, segB,
                                               (long)32768 * 768 / 8);
    transpose_f32_bf16<<<dim3(12, 12), 256, 0, stream>>>(W1 + 768 * 768, W1t, 768, 768);
    transpose_f32_bf16<<<dim3(6, 12), 256, 0, stream>>>(W2, W2t, 768, 384);

    // K1: qW1 = questions @ W1[:768] + b1 (fp32)
    gemm_bias_act<<<dim3(768 / BN, 128 / BM), 256, 0, stream>>>(
        questions, W1, b1, qW1, 128, 768, 768);
    // K2: H1b = gelu(segB @ W1t^T + qW1[bag])
    mfma_gemm_bt<<<dim3(6, 256), 256, 0, stream>>>(
        segB, W1t, nullptr, qW1, H1b, 32768, 768, 768, 1);
    // K3: H2b = gelu(H1b @ W2t^T + b2)
    mfma_gemm_bt<<<dim3(3, 256), 256, 0, stream>>>(
        H1b, W2t, b2, nullptr, H2b, 32768, 384, 768, 1);
    // K4: preds = softmax(H2b @ W3 + b3)
    l3_softmax<<<8192, 256, 0, stream>>>(H2b, W3, b3, preds);
    // K5: aggregation
    aggregate<<<128, 256, 0, stream>>>(preds, nseg, out);
}

// Round 3
// 353.102 us; speedup vs baseline: 2.6842x; 1.0663x over previous
//
#include <hip/hip_runtime.h>
#include <hip/hip_bf16.h>

// B=128, S=256, E=768, C=4; M = B*S = 32768.
// Pipeline:
//  conv:  segB[32768,768]bf16 = bf16(segments)
//  tr:    W1t[768,768]bf16 = bf16(W1[768:,:].T);  W2t[384,768]bf16 = bf16(W2.T)
//  K1:    qW1[128,768]f32 = questions @ W1[:768] + b1            (fp32 vector gemm)
//  K2:    H1b[32768,768]bf16 = gelu(segB @ W1t^T + qW1[bag])     (MFMA)
//  K3:    H2b[32768,384]bf16 = gelu(H1b @ W2t^T + b2)            (MFMA)
//  K4:    preds[32768,4]f32 = softmax(H2b @ W3 + b3)
//  K5:    out[128,4] = noisy-OR aggregation (scans)

typedef __attribute__((ext_vector_type(8))) short short8;
typedef __attribute__((ext_vector_type(8))) unsigned short ushort8;
typedef __attribute__((ext_vector_type(4))) float f32x4;

__device__ __forceinline__ unsigned short f2bf(float f) {
    union { float f; unsigned int u; } c; c.f = f;
    unsigned int u = c.u;
    unsigned int r = (u + 0x7FFFu + ((u >> 16) & 1u)) >> 16;  // RNE
    return (unsigned short)r;
}
__device__ __forceinline__ float bf2f(unsigned short u) {
    union { unsigned int u; float f; } c; c.u = ((unsigned int)u) << 16;
    return c.f;
}
__device__ __forceinline__ float gelu_exact(float x) {
    return 0.5f * x * (1.0f + erff(x * 0.70710678118654752440f));
}
// tanh-form gelu via HW exp/rcp: |err| <= ~3e-3, attenuated downstream.
__device__ __forceinline__ float gelu_fast(float x) {
    float x2 = x * x;
    float y2 = 1.5957691216057308f * (x + 0.044715f * x2 * x);  // 2*0.7978845608*(x+0.044715x^3)
    float e = __expf(y2);
    float t = 1.0f - 2.0f * __builtin_amdgcn_rcpf(e + 1.0f);    // tanh(y)
    return 0.5f * x * (1.0f + t);
}

typedef const __attribute__((address_space(1))) void* gas_t;
typedef __attribute__((address_space(3))) void* las_t;
__device__ __forceinline__ void g2l16(const void* g, void* l) {
    __builtin_amdgcn_global_load_lds((gas_t)g, (las_t)l, 16, 0, 0);
}

// ---------------- conversion kernels ----------------
__global__ __launch_bounds__(256) void conv_f32_bf16x8(
    const float4* __restrict__ in, unsigned short* __restrict__ out, long n8)
{
    long i = (long)blockIdx.x * 256 + threadIdx.x;
    if (i >= n8) return;
    float4 a = in[2 * i], b = in[2 * i + 1];
    ushort8 o;
    o[0] = f2bf(a.x); o[1] = f2bf(a.y); o[2] = f2bf(a.z); o[3] = f2bf(a.w);
    o[4] = f2bf(b.x); o[5] = f2bf(b.y); o[6] = f2bf(b.z); o[7] = f2bf(b.w);
    *(ushort8*)(out + i * 8) = o;
}

// out[c*R + r] = bf16(in[r*C + c])
__global__ __launch_bounds__(256) void transpose_f32_bf16(
    const float* __restrict__ in, unsigned short* __restrict__ out, int R, int C)
{
    __shared__ float t[64][65];
    int r0 = blockIdx.y * 64, c0 = blockIdx.x * 64;
    int tx = threadIdx.x & 63, ty = threadIdx.x >> 6;
    #pragma unroll
    for (int p = 0; p < 16; p++) {
        int row = ty * 16 + p;
        t[row][tx] = in[(size_t)(r0 + row) * C + c0 + tx];
    }
    __syncthreads();
    #pragma unroll
    for (int p = 0; p < 16; p++) {
        int orow = ty * 16 + p;
        out[(size_t)(c0 + orow) * R + r0 + tx] = f2bf(t[tx][orow]);
    }
}

// ---------------- fp32 vector GEMM (tiny K1) ----------------
#define BM 64
#define BN 64
#define BK 16
__global__ __launch_bounds__(256) void gemm_bias_act(
    const float* __restrict__ A, const float* __restrict__ Bw,
    const float* __restrict__ bias, float* __restrict__ Cout,
    int Mdim, int Ndim, int Kdim)
{
    __shared__ __align__(16) float As[BK][BM];
    __shared__ __align__(16) float Bs[BK][BN];
    const int tid = threadIdx.x;
    const int n0 = blockIdx.x * BN;
    const int m0 = blockIdx.y * BM;
    const int tn = tid & 15, tm = tid >> 4;
    float acc[4][4] = {};
    const int la_m = tid >> 2;
    const int la_k = (tid & 3) << 2;
    const int lb_k = tid >> 4;
    const int lb_n = (tid & 15) << 2;
    const float* Aptr = A + (size_t)(m0 + la_m) * Kdim + la_k;
    const float* Bptr = Bw + (size_t)lb_k * Ndim + n0 + lb_n;
    for (int k0 = 0; k0 < Kdim; k0 += BK) {
        float4 av = *(const float4*)(Aptr + k0);
        float4 bv = *(const float4*)(Bptr + (size_t)k0 * Ndim);
        As[la_k + 0][la_m] = av.x;
        As[la_k + 1][la_m] = av.y;
        As[la_k + 2][la_m] = av.z;
        As[la_k + 3][la_m] = av.w;
        *(float4*)&Bs[lb_k][lb_n] = bv;
        __syncthreads();
        #pragma unroll
        for (int k = 0; k < BK; k++) {
            float4 a = *(const float4*)&As[k][tm << 2];
            float4 b = *(const float4*)&Bs[k][tn << 2];
            float ar[4] = {a.x, a.y, a.z, a.w};
            float br[4] = {b.x, b.y, b.z, b.w};
            #pragma unroll
            for (int i = 0; i < 4; i++)
                #pragma unroll
                for (int j = 0; j < 4; j++)
                    acc[i][j] += ar[i] * br[j];
        }
        __syncthreads();
    }
    #pragma unroll
    for (int i = 0; i < 4; i++) {
        int row = m0 + (tm << 2) + i;
        int colBase = n0 + (tn << 2);
        float vals[4];
        #pragma unroll
        for (int j = 0; j < 4; j++)
            vals[j] = acc[i][j] + bias[colBase + j];
        *(float4*)&Cout[(size_t)row * Ndim + colBase] =
            make_float4(vals[0], vals[1], vals[2], vals[3]);
    }
}

// ---------------- bf16 MFMA GEMM, B^T input ----------------
// C[M,N] = act(A[M,K] @ Bt[N,K]^T + bias + rowAdd[m>>8]) -> bf16
__global__ __launch_bounds__(256) void mfma_gemm_bt(
    const unsigned short* __restrict__ A,
    const unsigned short* __restrict__ Bt,
    const float* __restrict__ bias,
    const float* __restrict__ rowAdd,
    unsigned short* __restrict__ Cout,
    int M, int N, int K, int applyGelu)
{
    // 32 KB: K-loop uses the first 16 KB as As/Bs; epilogue reuses all as C-tile.
    __shared__ __align__(16) unsigned short smem[128 * 128];
    unsigned short* As = smem;           // [128 rows][32 k]
    unsigned short* Bs = smem + 4096;    // [128 n]  [32 k]
    const int tid = threadIdx.x;
    const int wave = tid >> 6, lane = tid & 63;
    const int m0 = blockIdx.y * 128, n0 = blockIdx.x * 128;
    const int wm = (wave & 1) * 64, wn = (wave >> 1) * 64;

    f32x4 acc[4][4] = {};

    const int r0 = tid >> 2;
    const int c0 = (tid & 3) * 8;
    const unsigned short* Ag = A + (size_t)(m0 + r0) * K + c0;
    const unsigned short* Ag2 = Ag + (size_t)64 * K;
    const unsigned short* Bg = Bt + (size_t)(n0 + r0) * K + c0;
    const unsigned short* Bg2 = Bg + (size_t)64 * K;
    unsigned short* Al = As + tid * 8;
    unsigned short* Bl = Bs + tid * 8;

    const int fr = lane & 15, fq = lane >> 4;

    for (int k0 = 0; k0 < K; k0 += 32) {
        g2l16(Ag + k0, Al);
        g2l16(Ag2 + k0, Al + 2048);
        g2l16(Bg + k0, Bl);
        g2l16(Bg2 + k0, Bl + 2048);
        __syncthreads();

        short8 af[4], bfr[4];
        #pragma unroll
        for (int i = 0; i < 4; i++)
            af[i] = *(const short8*)&As[(wm + i * 16 + fr) * 32 + fq * 8];
        #pragma unroll
        for (int j = 0; j < 4; j++)
            bfr[j] = *(const short8*)&Bs[(wn + j * 16 + fr) * 32 + fq * 8];
        #pragma unroll
        for (int i = 0; i < 4; i++)
            #pragma unroll
            for (int j = 0; j < 4; j++)
                acc[i][j] = __builtin_amdgcn_mfma_f32_16x16x32_bf16(
                    af[i], bfr[j], acc[i][j], 0, 0, 0);
        __syncthreads();
    }

    // Epilogue: C/D layout col=lane&15, row=(lane>>4)*4+reg.
    // Write bf16 C-tile into LDS (disjoint per thread), then coalesced stores.
    const float* radd = rowAdd ? (rowAdd + (size_t)(m0 >> 8) * N) : nullptr;
    const int cn = lane & 15, cq = lane >> 4;
    #pragma unroll
    for (int j = 0; j < 4; j++) {
        int coll = wn + j * 16 + cn;
        int col = n0 + coll;
        float add = (bias ? bias[col] : 0.0f) + (radd ? radd[col] : 0.0f);
        #pragma unroll
        for (int i = 0; i < 4; i++) {
            int rowl = wm + i * 16 + cq * 4;
            #pragma unroll
            for (int r = 0; r < 4; r++) {
                float v = acc[i][j][r] + add;
                if (applyGelu) v = gelu_fast(v);
                smem[(rowl + r) * 128 + coll] = f2bf(v);
            }
        }
    }
    __syncthreads();
    #pragma unroll
    for (int it = 0; it < 8; it++) {
        int idx = it * 256 + tid;
        int r = idx >> 4, cc = (idx & 15) * 8;
        *(ushort8*)&Cout[(size_t)(m0 + r) * N + n0 + cc] =
            *(const ushort8*)&smem[r * 128 + cc];
    }
}

// ---------------- layer3 + softmax (bf16 input) ----------------
__global__ __launch_bounds__(256) void l3_softmax(
    const unsigned short* __restrict__ H2, const float* __restrict__ W3,
    const float* __restrict__ b3, float* __restrict__ preds)
{
    __shared__ float w3s[4 * 384];
    const int tid = threadIdx.x;
    for (int i = tid; i < 1536; i += 256) {
        int k = i >> 2, c = i & 3;
        w3s[c * 384 + k] = W3[i];
    }
    __syncthreads();
    const int wave = tid >> 6, lane = tid & 63;
    const int row = blockIdx.x * 4 + wave;

    float h[6];
    #pragma unroll
    for (int t = 0; t < 6; t++) h[t] = bf2f(H2[(size_t)row * 384 + lane + 64 * t]);

    float a0 = 0.f, a1 = 0.f, a2 = 0.f, a3 = 0.f;
    #pragma unroll
    for (int t = 0; t < 6; t++) {
        int k = lane + 64 * t;
        float hv = h[t];
        a0 += hv * w3s[k];
        a1 += hv * w3s[384 + k];
        a2 += hv * w3s[768 + k];
        a3 += hv * w3s[1152 + k];
    }
    #pragma unroll
    for (int off = 32; off > 0; off >>= 1) {
        a0 += __shfl_xor(a0, off, 64);
        a1 += __shfl_xor(a1, off, 64);
        a2 += __shfl_xor(a2, off, 64);
        a3 += __shfl_xor(a3, off, 64);
    }
    if (lane == 0) {
        float z0 = a0 + b3[0], z1 = a1 + b3[1], z2 = a2 + b3[2], z3 = a3 + b3[3];
        float m = fmaxf(fmaxf(z0, z1), fmaxf(z2, z3));
        float e0 = expf(z0 - m), e1 = expf(z1 - m), e2 = expf(z2 - m), e3 = expf(z3 - m);
        float inv = 1.0f / (e0 + e1 + e2 + e3);
        ((float4*)preds)[row] = make_float4(e0 * inv, e1 * inv, e2 * inv, e3 * inv);
    }
}

// ---------------- aggregation ----------------
__device__ __forceinline__ float4 f4mul(float4 a, float4 b) {
    return make_float4(a.x * b.x, a.y * b.y, a.z * b.z, a.w * b.w);
}
__device__ float4 scan_prod(float4 v, float4* buf, int tid) {
    __syncthreads();
    buf[tid] = v;
    __syncthreads();
    #pragma unroll
    for (int off = 1; off < 256; off <<= 1) {
        float4 o = (tid >= off) ? buf[tid - off] : make_float4(1.f, 1.f, 1.f, 1.f);
        __syncthreads();
        v = f4mul(v, o);
        buf[tid] = v;
        __syncthreads();
    }
    return v;
}

__global__ __launch_bounds__(256) void aggregate(
    const float* __restrict__ preds, const int* __restrict__ nseg,
    float* __restrict__ out)
{
    __shared__ float4 buf[256];
    const int b = blockIdx.x, tid = threadIdx.x;
    const int n = nseg[b];
    const float4 ones = make_float4(1.f, 1.f, 1.f, 1.f);

    float4 p = ((const float4*)preds)[b * 256 + tid];
    bool msk = tid < n;
    float e1 = p.x, e2 = e1 + p.y, e3 = e2 + p.z;
    float4 sm = msk ? make_float4(0.f, e1, e2, e3) : ones;

    scan_prod(sm, buf, tid);
    float4 pfx = (tid > 0) ? buf[tid - 1] : ones;
    __syncthreads();

    buf[255 - tid] = sm;
    __syncthreads();
    float4 rsm = buf[tid];
    scan_prod(rsm, buf, tid);
    float4 sfx = (tid < 255) ? buf[254 - tid] : ones;

    float4 L = f4mul(pfx, sfx);
    float4 cpL = scan_prod(L, buf, tid);

    float4 term = msk ? f4mul(p, cpL) : make_float4(0.f, 0.f, 0.f, 0.f);
    float4 pm = msk ? p : ones;

    __syncthreads();
    buf[tid] = term;
    __syncthreads();
    for (int off = 128; off > 0; off >>= 1) {
        if (tid < off) {
            float4 a = buf[tid], c = buf[tid + off];
            buf[tid] = make_float4(a.x + c.x, a.y + c.y, a.z + c.z, a.w + c.w);
        }
        __syncthreads();
    }
    float4 sum_t = buf[0];
    __syncthreads();

    buf[tid] = pm;
    __syncthreads();
    for (int off = 128; off > 0; off >>= 1) {
        if (tid < off) buf[tid] = f4mul(buf[tid], buf[tid + off]);
        __syncthreads();
    }
    if (tid == 0) {
        float4 pr = buf[0];
        ((float4*)out)[b] = make_float4(0.25f * sum_t.x + pr.x,
                                        0.25f * sum_t.y + pr.y,
                                        0.25f * sum_t.z + pr.z,
                                        0.25f * sum_t.w + pr.w);
    }
}

extern "C" void kernel_launch(void* const* d_in, const int* in_sizes, int n_in,
                              void* d_out, int out_size, void* d_ws, size_t ws_size,
                              hipStream_t stream) {
    (void)in_sizes; (void)n_in; (void)out_size; (void)ws_size;
    const float* questions = (const float*)d_in[0];
    const float* segments  = (const float*)d_in[1];
    const float* W1 = (const float*)d_in[2];
    const float* b1 = (const float*)d_in[3];
    const float* W2 = (const float*)d_in[4];
    const float* b2 = (const float*)d_in[5];
    const float* W3 = (const float*)d_in[6];
    const float* b3 = (const float*)d_in[7];
    const int*  nseg = (const int*)d_in[8];
    float* out = (float*)d_out;

    char* w = (char*)d_ws;
    float* qW1 = (float*)w;            w += (size_t)128 * 768 * 4;
    unsigned short* W1t = (unsigned short*)w; w += (size_t)768 * 768 * 2;
    unsigned short* W2t = (unsigned short*)w; w += (size_t)384 * 768 * 2;
    unsigned short* segB = (unsigned short*)w; w += (size_t)32768 * 768 * 2;
    unsigned short* H1b  = (unsigned short*)w; w += (size_t)32768 * 768 * 2;
    unsigned short* H2b  = (unsigned short*)w; w += (size_t)32768 * 384 * 2;
    float* preds = (float*)w;          w += (size_t)32768 * 4 * 4;

    conv_f32_bf16x8<<<12288, 256, 0, stream>>>((const float4*)segments, segB,
                                               (long)32768 * 768 / 8);
    transpose_f32_bf16<<<dim3(12, 12), 256, 0, stream>>>(W1 + 768 * 768, W1t, 768, 768);
    transpose_f32_bf16<<<dim3(6, 12), 256, 0, stream>>>(W2, W2t, 768, 384);

    gemm_bias_act<<<dim3(768 / BN, 128 / BM), 256, 0, stream>>>(
        questions, W1, b1, qW1, 128, 768, 768);
    mfma_gemm_bt<<<dim3(6, 256), 256, 0, stream>>>(
        segB, W1t, nullptr, qW1, H1b, 32768, 768, 768, 1);
    mfma_gemm_bt<<<dim3(3, 256), 256, 0, stream>>>(
        H1b, W2t, b2, nullptr, H2b, 32768, 384, 768, 1);
    l3_softmax<<<8192, 256, 0, stream>>>(H2b, W3, b3, preds);
    aggregate<<<128, 256, 0, stream>>>(preds, nseg, out);
}